// Round 1
// 61.051 us; speedup vs baseline: 1.0312x; 1.0312x over previous
//
#include <hip/hip_runtime.h>

#define HH 28
#define WW 28
#define NPIX 784
#define LWD 12
#define KLEN 25
#define PH (HH + 2 * LWD)   // 52 padded rows (pass 1)
#define PW (WW + 2 * LWD)   // 52 padded cols (pass 2)
#define NPAD (PH * WW)      // 1456 == HH*PW
#define NT 832              // 13 waves; 784 working lanes + init loop coverage

__global__ __launch_bounds__(NT) void canny_all(
    const float* __restrict__ x, const float* __restrict__ mask,
    const float* __restrict__ g, float* __restrict__ out)
{
    // H-zero-padded inputs: padded row pr holds input row pr-12 for pr in [12,40)
    __shared__ float spx[NPAD], spm[NPAD];
    // W-zero-padded pass-1 results: padded col pc holds value for input col pc-12
    __shared__ float t1x[NPAD], t1m[NPAD];
    __shared__ float sxs[NPIX], smag[NPIX];
    __shared__ unsigned rowHigh[HH], rowLow[HH], rowFinal[HH];
    __shared__ float sg[KLEN];

    const int tid = threadIdx.x;
    if (tid < KLEN) sg[tid] = g[tid];
    if (tid < HH) { rowHigh[tid] = 0u; rowLow[tid] = 0u; }

    // Init: load interior + zero pads for all four padded arrays (1456 elems each).
    for (int j = tid; j < NPAD; j += NT) {
        const int pr = j / WW;                 // padded row for spx/spm
        const int pc = j - pr * WW;
        float vx = 0.0f, vm = 0.0f;
        if (pr >= LWD && pr < LWD + HH) {
            vx = x[(pr - LWD) * WW + pc];
            vm = mask[(pr - LWD) * WW + pc];
        }
        spx[j] = vx; spm[j] = vm;
        const int c2 = j % PW;                 // padded col for t1x/t1m
        if (c2 < LWD || c2 >= LWD + WW) { t1x[j] = 0.0f; t1m[j] = 0.0f; }
    }
    __syncthreads();

    const int r = tid / WW, c = tid - (tid / WW) * WW;

    // ---- Gaussian pass 1: along H, branch-free (pad rows are zero) ----
    if (tid < NPIX) {
        float ax = 0.0f, am = 0.0f;
        #pragma unroll
        for (int i = 0; i < KLEN; ++i) {
            const float gv = sg[i];
            ax += gv * spx[tid + i * WW];      // padded row r+i == input row r-12+i
            am += gv * spm[tid + i * WW];
        }
        t1x[r * PW + c + LWD] = ax;
        t1m[r * PW + c + LWD] = am;
    }
    __syncthreads();

    // ---- Gaussian pass 2: along W, branch-free; xs = num/(bleed+1e-12) ----
    if (tid < NPIX) {
        float ax = 0.0f, am = 0.0f;
        const int base = r * PW + c;
        #pragma unroll
        for (int i = 0; i < KLEN; ++i) {
            const float gv = sg[i];
            ax += gv * t1x[base + i];          // padded col c+i == input col c-12+i
            am += gv * t1m[base + i];
        }
        sxs[tid] = ax / (am + 1e-12f);
    }
    __syncthreads();

    // ---- Sobel (deriv replicate-pad, then [1,2,1] replicate-pad), mag, erosion ----
    float isob = 0.0f, jsob = 0.0f, m = 0.0f, ai = 0.0f, aj = 0.0f;
    bool er = false;
    if (tid < NPIX) {
        const int rm = (r > 0) ? r - 1 : 0, rp = (r < HH - 1) ? r + 1 : r;
        const int cm = (c > 0) ? c - 1 : 0, cp = (c < WW - 1) ? c + 1 : c;
        const float x_mm = sxs[rm * WW + cm], x_m0 = sxs[rm * WW + c], x_mp = sxs[rm * WW + cp];
        const float x_0m = sxs[r  * WW + cm],                          x_0p = sxs[r  * WW + cp];
        const float x_pm = sxs[rp * WW + cm], x_p0 = sxs[rp * WW + c], x_pp = sxs[rp * WW + cp];
        // jsob: deriv along W then smooth along H
        const float dU = x_mp - x_mm, dC = x_0p - x_0m, dD = x_pp - x_pm;
        jsob = (dU + 2.0f * dC) + dD;
        // isob: deriv along H then smooth along W
        const float hL = x_pm - x_mm, hC = x_p0 - x_m0, hR = x_pp - x_mp;
        isob = (hL + 2.0f * hC) + hR;

        const float mag2 = isob * isob + jsob * jsob;
        m = sqrtf(mag2 + 1e-9f);          // THRES=0 multiply is a no-op (m > 0 always)
        smag[tid] = m;
        ai = fabsf(isob); aj = fabsf(jsob);

        bool er2 = (r >= 1) && (r <= HH - 2) && (c >= 1) && (c <= WW - 2);
        if (er2) {
            #pragma unroll
            for (int dr = -1; dr <= 1; ++dr)
                #pragma unroll
                for (int dc = -1; dc <= 1; ++dc)
                    er2 = er2 && (spm[(r + dr + LWD) * WW + (c + dc)] != 0.0f);
        }
        er = er2 && (mag2 > 0.0f);
    }
    __syncthreads();

    // ---- Sectors, lm, outputs s0..s3, lm, test; seed hysteresis bitmasks ----
    if (tid < NPIX) {
        const bool same = ((isob >= 0.0f) && (jsob >= 0.0f)) || ((isob <= 0.0f) && (jsob <= 0.0f));
        const bool opp  = ((isob <= 0.0f) && (jsob >= 0.0f)) || ((isob >= 0.0f) && (jsob <= 0.0f));
        const float GAMMA = 0.005f;
        float s0v = 0.0f, s1v = 0.0f, s2v = 0.0f, s3v = 0.0f;
        bool lmv = false;

        // NB(dr,dc): only evaluated where er==true (interior), so always in-bounds
        #define NB(dr, dc) (smag[(r + (dr)) * WW + (c + (dc))])

        if (er && same && (ai >= aj)) {              // 0-45
            const float w  = aj / (ai + 1e-9f);
            const float ip = NB(1, 1)   * w + NB(1, 0)   * (1.0f - w);
            const float im = NB(-1, -1) * w + NB(-1, 0)  * (1.0f - w);
            const float a = fmaxf(GAMMA - m + ip, 0.0f);
            const float b = fmaxf(GAMMA - m + im, 0.0f);
            s0v = fmaxf(a, b);
            lmv = (ip <= m) && (im <= m);
        }
        if (er && same && (ai <= aj)) {              // 45-90
            const float w  = ai / aj;                // pts1 => aj >= ai and mag2>0 => aj>0
            const float ip = NB(1, 1)   * w + NB(0, 1)  * (1.0f - w);
            const float im = NB(-1, -1) * w + NB(0, -1) * (1.0f - w);
            const float a = fmaxf(GAMMA - m + ip, 0.0f);
            const float b = fmaxf(GAMMA - m + im, 0.0f);
            s1v = fmaxf(a, b);
            lmv = (ip <= m) && (im <= m);
        }
        if (er && opp && (ai <= aj)) {               // 90-135 (bug: s2 reuses ip)
            const float w  = ai / aj;
            const float ip = NB(-1, 1) * w + NB(0, 1)  * (1.0f - w);
            const float im = NB(1, -1) * w + NB(0, -1) * (1.0f - w);
            const float a = fmaxf(GAMMA - m + ip, 0.0f);
            s2v = a;                                  // max(a, a)
            lmv = (ip <= m) && (im <= m);
        }
        if (er && opp && (ai >= aj)) {               // 135-180
            const float w  = aj / ai;
            const float ip = NB(-1, 1) * w + NB(-1, 0) * (1.0f - w);
            const float im = NB(1, -1) * w + NB(1, 0)  * (1.0f - w);
            const float a = fmaxf(GAMMA - m + ip, 0.0f);
            const float b = fmaxf(GAMMA - m + im, 0.0f);
            s3v = fmaxf(a, b);
            lmv = (ip <= m) && (im <= m);
        }
        #undef NB

        out[0 * NPIX + tid] = s0v;
        out[1 * NPIX + tid] = s1v;
        out[2 * NPIX + tid] = s2v;
        out[3 * NPIX + tid] = s3v;
        out[4 * NPIX + tid] = lmv ? 1.0f : 0.0f;
        out[5 * NPIX + tid] = 1.0f;

        if (lmv && (m >= 0.2f)) atomicOr(&rowHigh[r], 1u << c);
        if (lmv && (m >= 0.1f)) atomicOr(&rowLow[r],  1u << c);
    }
    __syncthreads();

    // ---- Hysteresis: up to 56 Jacobi iterations of (dilate & low), rows as bitmasks
    //      in wave 0 lanes, neighbor rows via shfl. Monotone fixpoint => exact
    //      early-exit once a full iteration changes nothing (result identical to 56). ----
    if (tid < 64) {
        unsigned cur = 0u, lo = 0u;
        if (tid < HH) { cur = rowHigh[tid]; lo = rowLow[tid]; }
        for (int it = 0; it < 2 * HH; ++it) {
            const unsigned up = __shfl(cur, (tid + 63) & 63, 64);  // lane r-1 (wraps to zeroed lanes)
            const unsigned dn = __shfl(cur, (tid + 1)  & 63, 64);  // lane r+1
            const unsigned mg = up | cur | dn;
            const unsigned nxt = (mg | (mg << 1) | (mg >> 1)) & lo;
            const bool chg = (nxt != cur);
            cur = nxt;
            if (!__any((int)chg)) break;   // wave-uniform vote: converged => iters 56 identical
        }
        if (tid < HH) rowFinal[tid] = cur;
    }
    __syncthreads();

    // ---- mag_out == mask_final exactly (mag - mag cancels) ----
    if (tid < NPIX) {
        out[6 * NPIX + tid] = (float)((rowFinal[r] >> c) & 1u);
    }
}

extern "C" void kernel_launch(void* const* d_in, const int* in_sizes, int n_in,
                              void* d_out, int out_size, void* d_ws, size_t ws_size,
                              hipStream_t stream) {
    const float* x    = (const float*)d_in[0];
    const float* mask = (const float*)d_in[1];
    const float* g    = (const float*)d_in[2];
    float* out = (float*)d_out;
    canny_all<<<1, NT, 0, stream>>>(x, mask, g, out);
}

// Round 2
// 59.813 us; speedup vs baseline: 1.0525x; 1.0207x over previous
//
#include <hip/hip_runtime.h>

#define HH 28
#define WW 28
#define NPIX 784
#define LWD 12
#define KLEN 25
#define PH (HH + 2 * LWD)   // 52 padded rows (pass 1)
#define PW (WW + 2 * LWD)   // 52 padded cols (pass 2)
#define NPAD (PH * WW)      // 1456 == HH*PW
#define NT 832              // 13 waves

__global__ __launch_bounds__(NT) void canny_all(
    const float* __restrict__ x, const float* __restrict__ mask,
    const float* __restrict__ g, float* __restrict__ out)
{
    // Interleaved {x, mask}: one ds_read_b64 per tap covers both arrays.
    __shared__ float2 sp[NPAD];   // H-zero-padded: padded row pr = input row pr-12
    __shared__ float2 t1[NPAD];   // W-zero-padded pass-1 result {gx, gm}
    __shared__ float sxs[NPIX], smag[NPIX];
    __shared__ unsigned rowHigh[HH], rowLow[HH];
    __shared__ float sg[KLEN];

    const int tid = threadIdx.x;
    if (tid < KLEN) sg[tid] = g[tid];
    if (tid < HH) { rowHigh[tid] = 0u; rowLow[tid] = 0u; }

    // Init: interior loads + zero pads (1456 float2 each array).
    for (int j = tid; j < NPAD; j += NT) {
        const int pr = j / WW;                 // padded row for sp
        const int pc = j - pr * WW;
        float vx = 0.0f, vm = 0.0f;
        if (pr >= LWD && pr < LWD + HH) {
            vx = x[(pr - LWD) * WW + pc];
            vm = mask[(pr - LWD) * WW + pc];
        }
        sp[j] = make_float2(vx, vm);
        const int c2 = j % PW;                 // padded col for t1
        if (c2 < LWD || c2 >= LWD + WW) t1[j] = make_float2(0.0f, 0.0f);
    }
    __syncthreads();

    const int r = tid / WW, c = tid - (tid / WW) * WW;

    // ---- Gaussian pass 1: along H, branch-free, packed {x,mask} ----
    if (tid < NPIX) {
        float ax = 0.0f, am = 0.0f;
        #pragma unroll
        for (int i = 0; i < KLEN; ++i) {
            const float gv = sg[i];
            const float2 t = sp[tid + i * WW]; // padded row r+i == input row r-12+i
            ax = fmaf(gv, t.x, ax);
            am = fmaf(gv, t.y, am);
        }
        t1[r * PW + c + LWD] = make_float2(ax, am);
    }
    __syncthreads();

    // ---- Gaussian pass 2: along W, branch-free; xs = num/(bleed+1e-12) ----
    if (tid < NPIX) {
        float ax = 0.0f, am = 0.0f;
        const int base = r * PW + c;
        #pragma unroll
        for (int i = 0; i < KLEN; ++i) {
            const float gv = sg[i];
            const float2 t = t1[base + i];     // padded col c+i == input col c-12+i
            ax = fmaf(gv, t.x, ax);
            am = fmaf(gv, t.y, am);
        }
        sxs[tid] = ax / (am + 1e-12f);
    }
    __syncthreads();

    // ---- Sobel (deriv replicate-pad, then [1,2,1] replicate-pad), mag, erosion ----
    float isob = 0.0f, jsob = 0.0f, m = 0.0f, ai = 0.0f, aj = 0.0f;
    bool er = false;
    if (tid < NPIX) {
        const int rm = (r > 0) ? r - 1 : 0, rp = (r < HH - 1) ? r + 1 : r;
        const int cm = (c > 0) ? c - 1 : 0, cp = (c < WW - 1) ? c + 1 : c;
        const float x_mm = sxs[rm * WW + cm], x_m0 = sxs[rm * WW + c], x_mp = sxs[rm * WW + cp];
        const float x_0m = sxs[r  * WW + cm],                          x_0p = sxs[r  * WW + cp];
        const float x_pm = sxs[rp * WW + cm], x_p0 = sxs[rp * WW + c], x_pp = sxs[rp * WW + cp];
        const float dU = x_mp - x_mm, dC = x_0p - x_0m, dD = x_pp - x_pm;
        jsob = (dU + 2.0f * dC) + dD;
        const float hL = x_pm - x_mm, hC = x_p0 - x_m0, hR = x_pp - x_mp;
        isob = (hL + 2.0f * hC) + hR;

        const float mag2 = isob * isob + jsob * jsob;
        m = sqrtf(mag2 + 1e-9f);          // THRES=0 multiply is a no-op (m > 0 always)
        smag[tid] = m;
        ai = fabsf(isob); aj = fabsf(jsob);

        bool er2 = (r >= 1) && (r <= HH - 2) && (c >= 1) && (c <= WW - 2);
        if (er2) {
            #pragma unroll
            for (int dr = -1; dr <= 1; ++dr)
                #pragma unroll
                for (int dc = -1; dc <= 1; ++dc)
                    er2 = er2 && (sp[(r + dr + LWD) * WW + (c + dc)].y != 0.0f);
        }
        er = er2 && (mag2 > 0.0f);
    }
    __syncthreads();

    // ---- Sectors, lm, outputs s0..s3, lm, test; seed hysteresis bitmasks ----
    if (tid < NPIX) {
        const bool same = ((isob >= 0.0f) && (jsob >= 0.0f)) || ((isob <= 0.0f) && (jsob <= 0.0f));
        const bool opp  = ((isob <= 0.0f) && (jsob >= 0.0f)) || ((isob >= 0.0f) && (jsob <= 0.0f));
        const float GAMMA = 0.005f;
        float s0v = 0.0f, s1v = 0.0f, s2v = 0.0f, s3v = 0.0f;
        bool lmv = false;

        // NB(dr,dc): only evaluated where er==true (interior), so always in-bounds
        #define NB(dr, dc) (smag[(r + (dr)) * WW + (c + (dc))])

        if (er && same && (ai >= aj)) {              // 0-45
            const float w  = aj / (ai + 1e-9f);
            const float ip = NB(1, 1)   * w + NB(1, 0)   * (1.0f - w);
            const float im = NB(-1, -1) * w + NB(-1, 0)  * (1.0f - w);
            const float a = fmaxf(GAMMA - m + ip, 0.0f);
            const float b = fmaxf(GAMMA - m + im, 0.0f);
            s0v = fmaxf(a, b);
            lmv = (ip <= m) && (im <= m);
        }
        if (er && same && (ai <= aj)) {              // 45-90
            const float w  = ai / aj;                // pts1 => aj >= ai and mag2>0 => aj>0
            const float ip = NB(1, 1)   * w + NB(0, 1)  * (1.0f - w);
            const float im = NB(-1, -1) * w + NB(0, -1) * (1.0f - w);
            const float a = fmaxf(GAMMA - m + ip, 0.0f);
            const float b = fmaxf(GAMMA - m + im, 0.0f);
            s1v = fmaxf(a, b);
            lmv = (ip <= m) && (im <= m);
        }
        if (er && opp && (ai <= aj)) {               // 90-135 (bug: s2 reuses ip)
            const float w  = ai / aj;
            const float ip = NB(-1, 1) * w + NB(0, 1)  * (1.0f - w);
            const float im = NB(1, -1) * w + NB(0, -1) * (1.0f - w);
            const float a = fmaxf(GAMMA - m + ip, 0.0f);
            s2v = a;                                  // max(a, a)
            lmv = (ip <= m) && (im <= m);
        }
        if (er && opp && (ai >= aj)) {               // 135-180
            const float w  = aj / ai;
            const float ip = NB(-1, 1) * w + NB(-1, 0) * (1.0f - w);
            const float im = NB(1, -1) * w + NB(1, 0)  * (1.0f - w);
            const float a = fmaxf(GAMMA - m + ip, 0.0f);
            const float b = fmaxf(GAMMA - m + im, 0.0f);
            s3v = fmaxf(a, b);
            lmv = (ip <= m) && (im <= m);
        }
        #undef NB

        out[0 * NPIX + tid] = s0v;
        out[1 * NPIX + tid] = s1v;
        out[2 * NPIX + tid] = s2v;
        out[3 * NPIX + tid] = s3v;
        out[4 * NPIX + tid] = lmv ? 1.0f : 0.0f;
        out[5 * NPIX + tid] = 1.0f;

        if (lmv && (m >= 0.2f)) atomicOr(&rowHigh[r], 1u << c);
        if (lmv && (m >= 0.1f)) atomicOr(&rowLow[r],  1u << c);
    }
    __syncthreads();   // last barrier: rowHigh/rowLow visible; waves 1..12 retire after this

    // ---- Hysteresis in wave 0 only: Jacobi (dilate & low) on row bitmasks via shfl.
    //      Monotone fixpoint => exact early-exit. Writes out[6] directly (no barrier). ----
    if (tid < 64) {
        unsigned cur = 0u, lo = 0u;
        if (tid < HH) { cur = rowHigh[tid]; lo = rowLow[tid]; }
        for (int it = 0; it < 2 * HH; ++it) {
            const unsigned up = __shfl(cur, (tid + 63) & 63, 64);  // lane r-1 (zeroed lanes wrap)
            const unsigned dn = __shfl(cur, (tid + 1)  & 63, 64);  // lane r+1
            const unsigned mg = up | cur | dn;
            const unsigned nxt = (mg | (mg << 1) | (mg >> 1)) & lo;
            const bool chg = (nxt != cur);
            cur = nxt;
            if (!__any((int)chg)) break;   // converged: iterations up to 56 are identical
        }
        if (tid < HH) {
            // mag_out == mask_final exactly (mag - mag cancels); row = 28 floats = 7 float4
            float4* op = (float4*)(out + 6 * NPIX + tid * WW);
            #pragma unroll
            for (int q = 0; q < 7; ++q) {
                op[q] = make_float4((float)((cur >> (4 * q + 0)) & 1u),
                                    (float)((cur >> (4 * q + 1)) & 1u),
                                    (float)((cur >> (4 * q + 2)) & 1u),
                                    (float)((cur >> (4 * q + 3)) & 1u));
            }
        }
    }
}

extern "C" void kernel_launch(void* const* d_in, const int* in_sizes, int n_in,
                              void* d_out, int out_size, void* d_ws, size_t ws_size,
                              hipStream_t stream) {
    const float* x    = (const float*)d_in[0];
    const float* mask = (const float*)d_in[1];
    const float* g    = (const float*)d_in[2];
    float* out = (float*)d_out;
    canny_all<<<1, NT, 0, stream>>>(x, mask, g, out);
}